// Round 7
// baseline (183.777 us; speedup 1.0000x reference)
//
#include <hip/hip_runtime.h>
#include <hip/hip_bf16.h>
#include <math.h>

// Problem constants (CPUEfficientCausalAttention): B=2, S=2048, HIDDEN=1024, H=16, hd=64
#define HIDDEN 1024
#define HEADS 16
#define HDIM 64
#define BATCH 2
#define SEQ 2048
#define BHN (BATCH*HEADS)   // 32
#define MTOT (BATCH*SEQ)    // 4096

typedef __attribute__((ext_vector_type(8))) short short8;   // 8 bf16 (16x16x32 A/B frag)
typedef __attribute__((ext_vector_type(4))) short short4v;  // 4 bf16 (16x16x16 A/B frag)
typedef __attribute__((ext_vector_type(4))) float floatx4;  // MFMA C/D frag

// global -> LDS direct (16B per lane; LDS dst is wave-uniform base, +lane*16 implicit)
#define GL2LDS(gsrc, ldst) __builtin_amdgcn_global_load_lds( \
    (const __attribute__((address_space(1))) void*)(gsrc), \
    (__attribute__((address_space(3))) void*)(ldst), 16, 0, 0)

__device__ __forceinline__ short f2bf(float f) {
  union { float f; unsigned u; } v; v.f = f;
  unsigned u = v.u;
  unsigned r = (u + 0x7fffu + ((u >> 16) & 1u)) >> 16;  // RNE
  return (short)r;
}
__device__ __forceinline__ float bf2f(short s) {
  unsigned u = ((unsigned)(unsigned short)s) << 16;
  return __builtin_bit_cast(float, u);
}

// One fused fp32->bf16 cast for x (1048576 vec4), qkv_w (786432), out_w (262144)
__global__ __launch_bounds__(256) void cvt3_f32_bf16(
    const float* __restrict__ a, const float* __restrict__ b, const float* __restrict__ c,
    short* __restrict__ oa, short* __restrict__ ob, short* __restrict__ oc) {
  int i = blockIdx.x * 256 + threadIdx.x;
  const float* src; short* dst; int j;
  if (i < 1048576)      { src = a; dst = oa; j = i; }
  else if (i < 1835008) { src = b; dst = ob; j = i - 1048576; }
  else                  { src = c; dst = oc; j = i - 1835008; }
  float4 f = reinterpret_cast<const float4*>(src)[j];
  short4 o;
  o.x = f2bf(f.x); o.y = f2bf(f.y); o.z = f2bf(f.z); o.w = f2bf(f.w);
  reinterpret_cast<short4*>(dst)[j] = o;
}

// C[M,N] = A[M,K] @ B[N,K]^T, bf16 in, fp32 accum.
// 128xBN tile, BK=64 (XOR-swizzled LDS rows of 128B keep b128 reads bank-minimal),
// 4 waves in 2x2, each wave 64x(BN/2).
// EPI==1 (BN=128): scatter qkv epilogue (q scaled by hd^-0.5*log2e, k row-major, v transposed)
// EPI==2: plain fp32 C row-major
template<int EPI, int BN>
__global__ __launch_bounds__(256) void gemm_bt(
    const short* __restrict__ A, const short* __restrict__ B,
    int M, int N, int K,
    float* __restrict__ outF,
    short* __restrict__ outQ, short* __restrict__ outK, short* __restrict__ outV)
{
  constexpr int WN = BN / 2;   // wave col extent
  constexpr int NI = BN / 32;  // 16-col tiles per wave
  __shared__ __align__(16) short As[128*64];
  __shared__ __align__(16) short Bs[BN*64];
  const int tid = threadIdx.x;
  const int wv = tid >> 6;
  const int lane = tid & 63;
  const int l15 = lane & 15;
  const int quad = lane >> 4;
  const int swl = l15 & 7;
  const int wm = wv >> 1, wn = wv & 1;
  const int row0 = blockIdx.y * 128, col0 = blockIdx.x * BN;

  floatx4 acc[4][NI];
#pragma unroll
  for (int i = 0; i < 4; i++)
#pragma unroll
    for (int j = 0; j < NI; j++) acc[i][j] = (floatx4){0.f, 0.f, 0.f, 0.f};

  for (int k0 = 0; k0 < K; k0 += 64) {
    // stage A [128][64] (1024 16B-chunks) and B [BN][64], XOR-swizzled on source col
#pragma unroll
    for (int rd = 0; rd < 4; ++rd) {
      int chunk = rd * 256 + tid;
      int r = chunk >> 3, c = ((chunk & 7) ^ (r & 7)) << 3;
      GL2LDS(A + (long)(row0 + r) * K + k0 + c, As + (rd * 256 + wv * 64) * 8);
    }
#pragma unroll
    for (int rd = 0; rd < BN / 32; ++rd) {
      int chunk = rd * 256 + tid;
      int r = chunk >> 3, c = ((chunk & 7) ^ (r & 7)) << 3;
      GL2LDS(B + (long)(col0 + r) * K + k0 + c, Bs + (rd * 256 + wv * 64) * 8);
    }
    __syncthreads();

    short8 af[4][2], bfr[NI][2];
#pragma unroll
    for (int mi = 0; mi < 4; mi++) {
      const short* ap = As + (wm * 64 + mi * 16 + l15) * 64;
#pragma unroll
      for (int kk = 0; kk < 2; kk++)
        af[mi][kk] = *(const short8*)(ap + (((kk * 4 + quad) ^ swl) << 3));
    }
#pragma unroll
    for (int ni = 0; ni < NI; ni++) {
      const short* bp = Bs + (wn * WN + ni * 16 + l15) * 64;
#pragma unroll
      for (int kk = 0; kk < 2; kk++)
        bfr[ni][kk] = *(const short8*)(bp + (((kk * 4 + quad) ^ swl) << 3));
    }
#pragma unroll
    for (int mi = 0; mi < 4; mi++)
#pragma unroll
      for (int ni = 0; ni < NI; ni++)
#pragma unroll
        for (int kk = 0; kk < 2; kk++)
          acc[mi][ni] = __builtin_amdgcn_mfma_f32_16x16x32_bf16(af[mi][kk], bfr[ni][kk], acc[mi][ni], 0, 0, 0);
    __syncthreads();
  }

  if (EPI == 2) {
#pragma unroll
    for (int mi = 0; mi < 4; mi++) {
      int rr = row0 + wm * 64 + mi * 16 + quad * 4;
#pragma unroll
      for (int ni = 0; ni < NI; ni++) {
        int cc = col0 + wn * WN + ni * 16 + l15;
#pragma unroll
        for (int r = 0; r < 4; r++)
          outF[(long)(rr + r) * N + cc] = acc[mi][ni][r];
      }
    }
  } else {
    // qkv scatter: j = t*1024 + h*64 + d ; i = b*2048 + s
#pragma unroll
    for (int mi = 0; mi < 4; mi++) {
      int rowg = row0 + wm * 64 + mi * 16 + quad * 4;
#pragma unroll
      for (int ni = 0; ni < NI; ni++) {
        int j = col0 + wn * WN + ni * 16 + l15;
        int t = j >> 10;
        int rem = j & 1023;
        int h = rem >> 6, d = rem & 63;
#pragma unroll
        for (int r = 0; r < 4; r++) {
          int i = rowg + r;
          int b = i >> 11, s = i & 2047;
          int bh = b * HEADS + h;
          float v = acc[mi][ni][r];
          // q scale = hd^-0.5 * log2(e) so flash can use raw v_exp_f32 (2^x)
          if (t == 0)      outQ[(bh * SEQ + s) * HDIM + d] = f2bf(v * 0.18033688011112042f);
          else if (t == 1) outK[(bh * SEQ + s) * HDIM + d] = f2bf(v);
          else             outV[(bh * HDIM + d) * SEQ + s] = f2bf(v);          // transposed
        }
      }
    }
  }
}

// K/V tile staging for 128-thread blocks: 64x64 K and 64x64 V^T, XOR-swizzled 16B chunks.
__device__ __forceinline__ void stage_kv(const short* __restrict__ kg,
                                         const short* __restrict__ vT,
                                         int bh, int kt, short* KsB, short* VsB,
                                         int tid, int wv) {
#pragma unroll
  for (int i = 0; i < 4; ++i) {
    int slot = i * 128 + tid;                 // 0..511
    int r = slot >> 3;
    int sc = ((slot & 7) ^ (r & 7)) << 3;
    GL2LDS(kg + (bh * SEQ + kt * 64 + r) * HDIM + sc, KsB + (i * 128 + wv * 64) * 8);
    GL2LDS(vT + (bh * HDIM + r) * SEQ + kt * 64 + sc, VsB + (i * 128 + wv * 64) * 8);
  }
}

// Flash attention v7: uniform work items + backfill.
// Static max ==> partial results over disjoint k-ranges combine by ADDITION (no rescale):
//   rt>=16: two k-half items/tile -> bf16 partial o + fp32 partial l in workspace.
//   rt<=15: one whole item/tile   -> final attn directly.
// 1536 one-dim blocks in 16 bands (longest first): band b = 64 split items (rt=31-b)
// + 32 whole items (rt=15-b). 2 waves/block, LDS 32KB -> 5 blocks/CU, grid 6/CU: backfill.
__global__ __launch_bounds__(128, 2) void flash_attn(
    const short* __restrict__ qg, const short* __restrict__ kg,
    const short* __restrict__ vT, short* __restrict__ attn,
    short* __restrict__ partO, float* __restrict__ partL)
{
  __shared__ __align__(16) short Ks[2][64 * 64];
  __shared__ __align__(16) short Vs[2][64 * 64];

  const int tid = threadIdx.x;
  const int wv = tid >> 6, lane = tid & 63;
  const int l15 = lane & 15, quad = lane >> 4;
  const int swl = l15 & 7;

  const int g = blockIdx.x;          // 0..1535
  const int band = g / 96, j = g % 96;
  int bh, rt, kt0, kt1, half = 0;
  bool psplit;
  if (j < 64) {                      // split item (rt in [16,31])
    rt = 31 - band; bh = j >> 1; half = j & 1;
    const int n = rt + 1, n0 = (n + 1) >> 1;
    kt0 = half ? n0 : 0; kt1 = half ? n : n0;
    psplit = true;
  } else {                           // whole item (rt in [0,15])
    rt = 15 - band; bh = j - 64;
    kt0 = 0; kt1 = rt + 1;
    psplit = false;
  }
  const int m0 = rt * 64 + wv * 32;  // wave's first q row

  // Q frags (persistent): B-operand for S^T: n=q=m0+mi*16+l15, k=d=kk*32+quad*8+j
  short8 aq[2][2];
#pragma unroll
  for (int mi = 0; mi < 2; mi++) {
    const short* qp = qg + (long)(bh * SEQ + m0 + mi * 16 + l15) * HDIM + quad * 8;
    aq[mi][0] = *(const short8*)qp;
    aq[mi][1] = *(const short8*)(qp + 32);
  }

  const short ONE = (short)0x3F80;  // bf16 1.0
  const short4v ones4 = {ONE, ONE, ONE, ONE};

  floatx4 o[2][4], lsum[2];
#pragma unroll
  for (int mi = 0; mi < 2; mi++) {
    lsum[mi] = (floatx4){0.f, 0.f, 0.f, 0.f};
#pragma unroll
    for (int nt = 0; nt < 4; nt++) o[mi][nt] = (floatx4){0.f, 0.f, 0.f, 0.f};
  }

  const int nk = kt1 - kt0;
  stage_kv(kg, vT, bh, kt0, Ks[0], Vs[0], tid, wv);

  for (int i = 0; i < nk; ++i) {
    const int kt = kt0 + i;
    __syncthreads();                         // drains GL2LDS (vmcnt 0): buf[i&1] ready
    const int buf = i & 1;
    if (i + 1 < nk)                          // prefetch next tile; drained at NEXT barrier
      stage_kv(kg, vT, bh, kt + 1, Ks[buf ^ 1], Vs[buf ^ 1], tid, wv);

    const short* KsB = Ks[buf];
    const short* VsB = Vs[buf];

    // ---- S^T = K . Q^T (16x16x32): D[row=kpos(quad*4+r)][col=q(l15)] ----
    floatx4 sc[2][4];
#pragma unroll
    for (int mi = 0; mi < 2; mi++)
#pragma unroll
      for (int nh = 0; nh < 4; nh++) sc[mi][nh] = (floatx4){0.f, 0.f, 0.f, 0.f};
#pragma unroll
    for (int nh = 0; nh < 4; nh++) {
      const short* kp = KsB + (nh * 16 + l15) * 64;
      short8 kf0 = *(const short8*)(kp + ((quad ^ swl) << 3));         // A: m=kpos, k=d 0..31
      short8 kf1 = *(const short8*)(kp + (((4 + quad) ^ swl) << 3));   // k=d 32..63
#pragma unroll
      for (int mi = 0; mi < 2; mi++) {
        sc[mi][nh] = __builtin_amdgcn_mfma_f32_16x16x32_bf16(kf0, aq[mi][0], sc[mi][nh], 0, 0, 0);
        sc[mi][nh] = __builtin_amdgcn_mfma_f32_16x16x32_bf16(kf1, aq[mi][1], sc[mi][nh], 0, 0, 0);
      }
    }

    // ---- softmax (static max, exp2 domain) + pack P into K=16 A-frags (registers) ----
    short4v pa[2][4];
#pragma unroll
    for (int mi = 0; mi < 2; mi++) {
      const int qrow = m0 + mi * 16 + l15;
      const bool full = (kt * 64 + 63) <= (m0 + mi * 16);   // wave-uniform per mi
#pragma unroll
      for (int nh = 0; nh < 4; nh++) {
        unsigned u[4];
#pragma unroll
        for (int r = 0; r < 4; r++) {
          float pe = __builtin_amdgcn_exp2f(sc[mi][nh][r]);
          if (!full) {
            const int kpos = kt * 64 + nh * 16 + quad * 4 + r;
            pe = (kpos <= qrow) ? pe : 0.f;
          }
          u[r] = __builtin_bit_cast(unsigned, pe) & 0xffff0000u;  // trunc to bf16
        }
        uint2 w;
        w.x = (u[0] >> 16) | u[1];   // k = quad*4 + {0,1}
        w.y = (u[2] >> 16) | u[3];   // k = quad*4 + {2,3}
        pa[mi][nh] = __builtin_bit_cast(short4v, w);
      }
    }

    // ---- P @ V and P @ ones via 16x16x16 MFMA (P direct from registers) ----
#pragma unroll
    for (int kk = 0; kk < 4; kk++) {
      short4v bv[4];
#pragma unroll
      for (int nt = 0; nt < 4; nt++) {
        const int ch = (kk * 2 + (quad >> 1)) ^ swl;   // 16B-chunk swizzle
        bv[nt] = *(const short4v*)(VsB + (nt * 16 + l15) * 64 + (ch << 3) + ((quad & 1) << 2));
      }
#pragma unroll
      for (int mi = 0; mi < 2; mi++) {
        lsum[mi] = __builtin_amdgcn_mfma_f32_16x16x16bf16_1k(pa[mi][kk], ones4, lsum[mi], 0, 0, 0);
#pragma unroll
        for (int nt = 0; nt < 4; nt++)
          o[mi][nt] = __builtin_amdgcn_mfma_f32_16x16x16bf16_1k(pa[mi][kk], bv[nt], o[mi][nt], 0, 0, 0);
      }
    }
  }

  if (!psplit) {
    const int b = bh >> 4, h = bh & 15;
#pragma unroll
    for (int mi = 0; mi < 2; mi++)
#pragma unroll
      for (int r = 0; r < 4; r++) {
        const float inv = 1.0f / lsum[mi][r];
        const int s = m0 + mi * 16 + quad * 4 + r;
#pragma unroll
        for (int nt = 0; nt < 4; nt++)
          attn[(long)(b * SEQ + s) * HIDDEN + h * HDIM + nt * 16 + l15] = f2bf(o[mi][nt][r] * inv);
      }
  } else {
    // partial epilogue: un-normalized o as bf16, l as fp32
    const int set = (bh * 16 + (rt - 16)) * 2 + half;
    short* po = partO + (long)set * 4096;
    float* pl = partL + set * 64;
#pragma unroll
    for (int mi = 0; mi < 2; mi++)
#pragma unroll
      for (int r = 0; r < 4; r++) {
        const int qloc = wv * 32 + mi * 16 + quad * 4 + r;
#pragma unroll
        for (int nt = 0; nt < 4; nt++)
          po[qloc * 64 + nt * 16 + l15] = f2bf(o[mi][nt][r]);
        if (l15 == 0) pl[qloc] = lsum[mi][r];
      }
  }
}

// Combine split partials: attn = (oA + oB) / (lA + lB). 512 q-tiles (bh, rt in [16,32)).
__global__ __launch_bounds__(256) void combine(
    const short* __restrict__ partO, const float* __restrict__ partL,
    short* __restrict__ attn)
{
  const int g = blockIdx.x;          // 0..511
  const int bh = g & 31, r16 = g >> 5;
  const int rt = 16 + r16;
  const int setA = (bh * 16 + r16) * 2;
  const int row = threadIdx.x >> 2, seg = (threadIdx.x & 3) << 4;
  const short* pa = partO + (long)setA * 4096 + row * 64 + seg;
  const short* pb = pa + 4096;
  const float inv = 1.0f / (partL[setA * 64 + row] + partL[(setA + 1) * 64 + row]);
  const int b = bh >> 4, h = bh & 15;
  const int s = rt * 64 + row;
  short* dst = attn + (long)(b * SEQ + s) * HIDDEN + h * HDIM + seg;
  short8 va0 = *(const short8*)pa, vb0 = *(const short8*)pb;
  short8 va1 = *(const short8*)(pa + 8), vb1 = *(const short8*)(pb + 8);
  short8 o0, o1;
#pragma unroll
  for (int i = 0; i < 8; i++) {
    o0[i] = f2bf((bf2f(va0[i]) + bf2f(vb0[i])) * inv);
    o1[i] = f2bf((bf2f(va1[i]) + bf2f(vb1[i])) * inv);
  }
  *(short8*)dst = o0;
  *(short8*)(dst + 8) = o1;
}

extern "C" void kernel_launch(void* const* d_in, const int* in_sizes, int n_in,
                              void* d_out, int out_size, void* d_ws, size_t ws_size,
                              hipStream_t stream) {
  const float* x     = (const float*)d_in[0];  // [2,2048,1024]
  const float* qkv_w = (const float*)d_in[1];  // [3072,1024]
  const float* out_w = (const float*)d_in[2];  // [1024,1024]
  float* out = (float*)d_out;                  // [2,2048,1024] fp32

  short* xb    = (short*)d_ws;                      // 4096*1024
  short* wqb   = xb  + MTOT * HIDDEN;               // 3072*1024
  short* wob   = wqb + 3 * HIDDEN * HIDDEN;         // 1024*1024
  short* qB    = wob + HIDDEN * HIDDEN;             // 32*2048*64
  short* kB    = qB  + BHN * SEQ * HDIM;
  short* vTB   = kB  + BHN * SEQ * HDIM;
  short* attn  = vTB + BHN * SEQ * HDIM;            // 4096*1024
  short* partO = attn + MTOT * HIDDEN;              // 1024 sets * 4096 bf16
  float* partL = (float*)(partO + 1024 * 4096);     // 1024 sets * 64 fp32

  // fused bf16 casts: (4096+3072+1024)*1024/4 = 2097152 vec4 -> 8192 blocks
  cvt3_f32_bf16<<<dim3(8192), dim3(256), 0, stream>>>(x, qkv_w, out_w, xb, wqb, wob);

  // QKV projection: M=4096, N=3072, K=1024, BK=64
  gemm_bt<1, 128><<<dim3(3 * HIDDEN / 128, MTOT / 128), dim3(256), 0, stream>>>(
      xb, wqb, MTOT, 3 * HIDDEN, HIDDEN, nullptr, qB, kB, vTB);

  // causal attention: 1536 uniform items (longest bands first), 2-wave blocks
  flash_attn<<<dim3(1536), dim3(128), 0, stream>>>(qB, kB, vTB, attn, partO, partL);
  combine<<<dim3(512), dim3(256), 0, stream>>>(partO, partL, attn);

  // output projection: M=4096, N=1024, K=1024 (128x64 tiles -> 512 blocks), BK=64
  gemm_bt<2, 64><<<dim3(HIDDEN / 64, MTOT / 128), dim3(256), 0, stream>>>(
      attn, wob, MTOT, HIDDEN, HIDDEN, out, nullptr, nullptr, nullptr);
}